// Round 11
// baseline (172.876 us; speedup 1.0000x reference)
//
#include <hip/hip_runtime.h>

#define B_ 16
#define T_ 2048
#define D_ 512
#define SCALE_LOG2E 0.18033688f   // (1/8) * log2(e)

typedef __bf16 bf16x8 __attribute__((ext_vector_type(8)));
typedef float  f32x4  __attribute__((ext_vector_type(4)));

__device__ inline unsigned short f2bf(float f){
    union { float f; unsigned u; } x; x.f = f;
    unsigned r = x.u + 0x7fffu + ((x.u >> 16) & 1u);   // RNE
    return (unsigned short)(r >> 16);
}

__device__ inline bf16x8 ldfrag(const unsigned short* p){
    uint4 v = *reinterpret_cast<const uint4*>(p);
    return __builtin_bit_cast(bf16x8, v);
}

// ws layout (bytes):
//   WcT  @ 0       : 144x512 bf16 (cols: 64 Wq^T | 64 Wk^T | sumWq | sumWk | sumWv | 13 zero)
//   bsum @ 147456  : float[16] (Σbq, Σbk, Σbv)
//   Qb   @ 262144  : 32768x64 bf16, pre-scaled by SCALE_LOG2E
//   Kb   @ 4456448 : 32768x64 bf16, masked rows zeroed
//   wvp  @ 8650752 : float[32768] = qmask*vsum

// ---------------- setup: build WcT + bsum, zero out ----------------------------------
__global__ void setup_kernel(const float* __restrict__ Wq, const float* __restrict__ Wk,
                             const float* __restrict__ Wv, const float* __restrict__ bq,
                             const float* __restrict__ bk, const float* __restrict__ bv,
                             unsigned short* __restrict__ WcT, float* __restrict__ bsum,
                             float* __restrict__ out)
{
    int e = blockIdx.x * 256 + threadIdx.x;
    if (e < 73728){                       // 144*512
        int j = e >> 9, d = e & 511;
        float v;
        if (j < 64)       v = Wq[d * 64 + j];
        else if (j < 128) v = Wk[d * 64 + (j - 64)];
        else if (j < 131){
            const float* src = (j == 128) ? Wq : (j == 129) ? Wk : Wv;
            const float4* p = reinterpret_cast<const float4*>(&src[d * 64]);
            v = 0.f;
            #pragma unroll
            for (int i = 0; i < 16; i++){ float4 t = p[i]; v += (t.x + t.y) + (t.z + t.w); }
        }
        else v = 0.f;
        WcT[j * 512 + d] = f2bf(v);
    } else if (e < 73744){
        int mm = e - 73728;
        float s = 0.f;
        const float* src = (mm == 0) ? bq : (mm == 1) ? bk : bv;
        if (mm < 3){
            const float4* p = reinterpret_cast<const float4*>(src);
            #pragma unroll
            for (int i = 0; i < 16; i++){ float4 t = p[i]; s += (t.x + t.y) + (t.z + t.w); }
        }
        bsum[mm] = s;
    } else if (e < 81936){
        out[e - 73744] = 0.f;             // 8192 floats
    }
}

// ---------------- proj: no-LDS-staging GEMM with K-SPLIT for 2x TLP ------------------
// 512 blocks x 512 threads; wave (mh,kh): rows mh*16, K-half kh*256 (8 iters).
// 4096 waves = 16 waves/CU (2x R10) to cover the HBM/L2 load latency that R10's
// counters showed exposed (MfmaUtil 3.3%, VALUBusy 12.6%, occ 17%).
// A/B fragments load straight to registers (contiguous per lane); no k-loop barriers.
// One 36 KB LDS exchange combines the K-halves, then kh=0 waves run the epilogue.
__global__ __launch_bounds__(512) void proj_kernel(
    const float* __restrict__ inp, const unsigned short* __restrict__ WcT,
    const float* __restrict__ bq, const float* __restrict__ bk,
    const float* __restrict__ bsum,
    unsigned short* __restrict__ Qb, unsigned short* __restrict__ Kb,
    float* __restrict__ wvp)
{
    __shared__ __align__(16) float xch[4 * 64 * 36];       // kh=1 partials, 36 KB
    const int tid  = threadIdx.x;
    const int lane = tid & 63, wvid = tid >> 6;
    const int m = lane & 15, q = lane >> 4;
    const int mh = wvid & 3, kh = wvid >> 2;
    const int r0 = blockIdx.x * 64 + mh * 16;              // wave's 16 rows

    const float* ap = &inp[(size_t)(r0 + m) * 512 + kh * 256 + q * 8];   // A: 8 fp32/lane
    const unsigned short* bp = &WcT[m * 512 + kh * 256 + q * 8];         // B tile t: +t*8192

    f32x4 acc[9];
    #pragma unroll
    for (int t = 0; t < 9; t++) acc[t] = (f32x4){0.f, 0.f, 0.f, 0.f};

    // prefetch iter 0
    float4 f0 = *reinterpret_cast<const float4*>(ap);
    float4 f1 = *reinterpret_cast<const float4*>(ap + 4);
    uint4 bfr[9];
    #pragma unroll
    for (int t = 0; t < 9; t++) bfr[t] = *reinterpret_cast<const uint4*>(bp + t * 8192);

    for (int it = 0; it < 8; it++){
        uint4 au;
        au.x = f2bf(f0.x) | ((unsigned)f2bf(f0.y) << 16);
        au.y = f2bf(f0.z) | ((unsigned)f2bf(f0.w) << 16);
        au.z = f2bf(f1.x) | ((unsigned)f2bf(f1.y) << 16);
        au.w = f2bf(f1.z) | ((unsigned)f2bf(f1.w) << 16);
        bf16x8 a = __builtin_bit_cast(bf16x8, au);
        uint4 bcur[9];
        #pragma unroll
        for (int t = 0; t < 9; t++) bcur[t] = bfr[t];
        if (it < 7){                                       // prefetch next iter
            const int kn = (it + 1) * 32;
            f0 = *reinterpret_cast<const float4*>(ap + kn);
            f1 = *reinterpret_cast<const float4*>(ap + kn + 4);
            #pragma unroll
            for (int t = 0; t < 9; t++)
                bfr[t] = *reinterpret_cast<const uint4*>(bp + t * 8192 + kn);
        }
        #pragma unroll
        for (int t = 0; t < 9; t++)
            acc[t] = __builtin_amdgcn_mfma_f32_16x16x32_bf16(
                         a, __builtin_bit_cast(bf16x8, bcur[t]), acc[t], 0, 0, 0);
    }

    // K-combine: kh=1 publishes partials; kh=0 accumulates (one barrier total).
    if (kh == 1){
        float* dst = &xch[(mh * 64 + lane) * 36];
        #pragma unroll
        for (int t = 0; t < 9; t++)
            *reinterpret_cast<f32x4*>(dst + t * 4) = acc[t];
    }
    __syncthreads();
    if (kh == 0){
        const float* src = &xch[(mh * 64 + lane) * 36];
        #pragma unroll
        for (int t = 0; t < 9; t++){
            f32x4 p = *reinterpret_cast<const f32x4*>(src + t * 4);
            acc[t][0] += p[0]; acc[t][1] += p[1]; acc[t][2] += p[2]; acc[t][3] += p[3];
        }

        // epilogue (R10 verbatim): wave-local, kz via shfl within row-group
        float bqv[4], bkv[4];
        #pragma unroll
        for (int t = 0; t < 4; t++){ bqv[t] = bq[t * 16 + m]; bkv[t] = bk[t * 16 + m]; }
        const float bs = bsum[m];         // m: 0=Σbq 1=Σbk 2=Σbv

        #pragma unroll
        for (int i = 0; i < 4; i++){
            size_t r = (size_t)r0 + q * 4 + i;
            float val = acc[8][i] + bs;
            float qsv = __shfl(val, (lane & 48));
            float ksv = __shfl(val, (lane & 48) | 1);
            float vsv = __shfl(val, (lane & 48) | 2);
            float kz  = (ksv == 0.f) ? 0.f : 1.f;  // zero masked K rows -> score 0 (~ref 1e-8)
            #pragma unroll
            for (int t = 0; t < 4; t++)
                Qb[r * 64 + t * 16 + m] = f2bf((acc[t][i] + bqv[t]) * SCALE_LOG2E);
            #pragma unroll
            for (int t = 0; t < 4; t++)
                Kb[r * 64 + t * 16 + m] = f2bf((acc[t + 4][i] + bkv[t]) * kz);
            if (m == 0)
                wvp[r] = (qsv == 0.f) ? 0.f : vsv; // qmask * vsum
        }
    }
}

// ---------------- attn_out: full-K per block -> c in LDS -> out contraction ----------
// Block: (b, 128 q-rows), 8 waves; wave w owns rows t0+w*16, loops ALL 2048 keys.
// K tiles double-buffered in frag order (1 barrier/tile). Then out phase in-block.
__global__ __launch_bounds__(512) void attn_out_kernel(
    const float* __restrict__ inp,
    const unsigned short* __restrict__ Qb, const unsigned short* __restrict__ Kb,
    const float* __restrict__ wvp, float* __restrict__ out)
{
    __shared__ __align__(16) unsigned short Kf[2][8 * 512]; // 2 bufs x 8 chunks x 1KB
    __shared__ float csh[128];
    const int tid = threadIdx.x;
    const int lane = tid & 63, wvid = tid >> 6;             // 8 waves
    const int m = lane & 15, q = lane >> 4;
    const int b  = blockIdx.y;
    const int t0 = blockIdx.x * 128;                        // block's 128 q-rows
    const size_t base = (size_t)b * T_;

    // wave's 16 q-rows
    const unsigned short* qp = &Qb[(base + t0 + wvid * 16 + m) * 64 + q * 8];
    bf16x8 a0 = ldfrag(qp), a1 = ldfrag(qp + 32);

    // wave wvid stages chunk wvid: key rows (wvid>>1)*16..+16, k-half (wvid&1)
    const unsigned short* ksrc = &Kb[(base + (wvid >> 1) * 16 + m) * 64 + (wvid & 1) * 32 + q * 8];
    const int k_off = wvid * 512 + lane * 8;
    uint4 stg = *reinterpret_cast<const uint4*>(ksrc);

    float num[4] = {0,0,0,0}, den[4] = {0,0,0,0};

    for (int it = 0; it < 32; it++){
        const int p = it & 1;
        *reinterpret_cast<uint4*>(&Kf[p][k_off]) = stg;
        __syncthreads();                  // dbuf: single barrier per tile
        if (it < 31) stg = *reinterpret_cast<const uint4*>(ksrc + (it + 1) * 4096);
        float w[4];
        #pragma unroll
        for (int st = 0; st < 4; st++) w[st] = wvp[base + it * 64 + st * 16 + m];
        #pragma unroll
        for (int st = 0; st < 4; st++){
            bf16x8 b0 = ldfrag(&Kf[p][(st * 2    ) * 512 + lane * 8]);
            bf16x8 b1 = ldfrag(&Kf[p][(st * 2 + 1) * 512 + lane * 8]);
            f32x4 z = (f32x4){0.f,0.f,0.f,0.f};
            z = __builtin_amdgcn_mfma_f32_16x16x32_bf16(a0, b0, z, 0, 0, 0);
            z = __builtin_amdgcn_mfma_f32_16x16x32_bf16(a1, b1, z, 0, 0, 0);
            float wst = w[st];
            #pragma unroll
            for (int i = 0; i < 4; i++){
                float e = exp2f(z[i]);                    // scale pre-folded into Qb
                den[i] += e;
                num[i] = fmaf(e, wst, num[i]);
            }
        }
    }
    #pragma unroll
    for (int s = 1; s < 16; s <<= 1){
        #pragma unroll
        for (int i = 0; i < 4; i++){
            num[i] += __shfl_xor(num[i], s);
            den[i] += __shfl_xor(den[i], s);
        }
    }
    __syncthreads();                      // Kf no longer needed; csh about to be written
    if (m == 0){
        #pragma unroll
        for (int i = 0; i < 4; i++)
            csh[wvid * 16 + q * 4 + i] = num[i] / den[i];
    }
    __syncthreads();

    // out phase: thread tid owns column tid; loop the block's 128 rows
    const float* ip = inp + (base + t0) * 512 + tid;
    float a = 0.f;
    #pragma unroll 8
    for (int t = 0; t < 128; t++)
        a = fmaf(ip[(size_t)t * 512], csh[t], a);
    atomicAdd(&out[b * 512 + tid], a);
}

extern "C" void kernel_launch(void* const* d_in, const int* in_sizes, int n_in,
                              void* d_out, int out_size, void* d_ws, size_t ws_size,
                              hipStream_t stream)
{
    const float* inp = (const float*)d_in[0];
    const float* Wq  = (const float*)d_in[1];
    const float* bq  = (const float*)d_in[2];
    const float* Wk  = (const float*)d_in[3];
    const float* bk  = (const float*)d_in[4];
    const float* Wv  = (const float*)d_in[5];
    const float* bv  = (const float*)d_in[6];
    float* out = (float*)d_out;

    char* ws = (char*)d_ws;
    unsigned short* WcT = (unsigned short*)(ws);
    float* bsum         = (float*)(ws + 147456);
    unsigned short* Qb  = (unsigned short*)(ws + 262144);
    unsigned short* Kb  = (unsigned short*)(ws + 4456448);
    float* wvp          = (float*)(ws + 8650752);

    setup_kernel<<<321, 256, 0, stream>>>(Wq, Wk, Wv, bq, bk, bv, WcT, bsum, out);
    proj_kernel<<<512, 512, 0, stream>>>(inp, WcT, bq, bk, bsum, Qb, Kb, wvp);
    attn_out_kernel<<<dim3(16, 16), 512, 0, stream>>>(inp, Qb, Kb, wvp, out);
}

// Round 13
// 153.507 us; speedup vs baseline: 1.1262x; 1.1262x over previous
//
#include <hip/hip_runtime.h>

#define B_ 16
#define T_ 2048
#define D_ 512
#define SCALE_LOG2E 0.18033688f   // (1/8) * log2(e)

typedef __bf16 bf16x8 __attribute__((ext_vector_type(8)));
typedef float  f32x4  __attribute__((ext_vector_type(4)));

__device__ inline unsigned short f2bf(float f){
    union { float f; unsigned u; } x; x.f = f;
    unsigned r = x.u + 0x7fffu + ((x.u >> 16) & 1u);   // RNE
    return (unsigned short)(r >> 16);
}

__device__ inline bf16x8 ldfrag(const unsigned short* p){
    uint4 v = *reinterpret_cast<const uint4*>(p);
    return __builtin_bit_cast(bf16x8, v);
}

// ws layout (bytes):
//   WcT  @ 0       : 144x512 bf16 (cols: 64 Wq^T | 64 Wk^T | sumWq | sumWk | sumWv | 13 zero)
//   bsum @ 147456  : float[16] (Σbq, Σbk, Σbv)
//   Qb   @ 262144  : 32768x64 bf16, pre-scaled by SCALE_LOG2E
//   Kb   @ 4456448 : 32768x64 bf16, masked rows zeroed
//   wvp  @ 8650752 : float[32768] = qmask*vsum

// ---------------- setup: build WcT + bsum, zero out ----------------------------------
__global__ void setup_kernel(const float* __restrict__ Wq, const float* __restrict__ Wk,
                             const float* __restrict__ Wv, const float* __restrict__ bq,
                             const float* __restrict__ bk, const float* __restrict__ bv,
                             unsigned short* __restrict__ WcT, float* __restrict__ bsum,
                             float* __restrict__ out)
{
    int e = blockIdx.x * 256 + threadIdx.x;
    if (e < 73728){                       // 144*512
        int j = e >> 9, d = e & 511;
        float v;
        if (j < 64)       v = Wq[d * 64 + j];
        else if (j < 128) v = Wk[d * 64 + (j - 64)];
        else if (j < 131){
            const float* src = (j == 128) ? Wq : (j == 129) ? Wk : Wv;
            const float4* p = reinterpret_cast<const float4*>(&src[d * 64]);
            v = 0.f;
            #pragma unroll
            for (int i = 0; i < 16; i++){ float4 t = p[i]; v += (t.x + t.y) + (t.z + t.w); }
        }
        else v = 0.f;
        WcT[j * 512 + d] = f2bf(v);
    } else if (e < 73744){
        int mm = e - 73728;
        float s = 0.f;
        const float* src = (mm == 0) ? bq : (mm == 1) ? bk : bv;
        if (mm < 3){
            const float4* p = reinterpret_cast<const float4*>(src);
            #pragma unroll
            for (int i = 0; i < 16; i++){ float4 t = p[i]; s += (t.x + t.y) + (t.z + t.w); }
        }
        bsum[mm] = s;
    } else if (e < 81936){
        out[e - 73744] = 0.f;             // 8192 floats
    }
}

// ---------------- proj: (32768 x 512) @ (512 x 144) -> Qb, Kb, wvp (R5/R9 exact) -----
__global__ __launch_bounds__(256) void proj_kernel(
    const float* __restrict__ inp, const unsigned short* __restrict__ WcT,
    const float* __restrict__ bq, const float* __restrict__ bk,
    const float* __restrict__ bsum,
    unsigned short* __restrict__ Qb, unsigned short* __restrict__ Kb,
    float* __restrict__ wvp)
{
    __shared__ __align__(16) unsigned short Af[4 * 512];    // 4 m-chunks x 1KB
    __shared__ __align__(16) unsigned short Bf[9 * 512];    // 9 n-tiles x 1KB
    __shared__ float kzsh[64];
    const int tid  = threadIdx.x;
    const int r0   = blockIdx.x * 64;
    const int lane = tid & 63, wvid = tid >> 6;
    const int m = lane & 15, q = lane >> 4;
    const int mh = wvid >> 1, nh = wvid & 1;

    const int ar = tid >> 2, aseg = tid & 3;
    unsigned short* a_dst = &Af[(ar >> 4) * 512 + (aseg * 16 + (ar & 15)) * 8];
    const float* a_src = &inp[(size_t)(r0 + ar) * 512 + aseg * 8];
    const unsigned short* b_src0 = &WcT[(((tid      ) >> 6) * 16 + (tid & 15)) * 512 + ((tid >> 4) & 3) * 8];
    const unsigned short* b_src1 = &WcT[(((tid + 256) >> 6) * 16 + (tid & 15)) * 512 + ((tid >> 4) & 3) * 8];
    const unsigned short* b_src2 = &WcT[(((tid + 512) >> 6) * 16 + (tid & 15)) * 512 + ((tid >> 4) & 3) * 8];
    uint4* b_dst0 = reinterpret_cast<uint4*>(&Bf[(tid      ) * 8]);
    uint4* b_dst1 = reinterpret_cast<uint4*>(&Bf[(tid + 256) * 8]);
    uint4* b_dst2 = reinterpret_cast<uint4*>(&Bf[(tid + 512) * 8]);

    f32x4 acc[5][2];
    #pragma unroll
    for (int t = 0; t < 5; t++){
        acc[t][0] = (f32x4){0.f, 0.f, 0.f, 0.f};
        acc[t][1] = (f32x4){0.f, 0.f, 0.f, 0.f};
    }

    float4 ga0 = *reinterpret_cast<const float4*>(a_src);
    float4 ga1 = *reinterpret_cast<const float4*>(a_src + 4);
    uint4 gb0 = *reinterpret_cast<const uint4*>(b_src0);
    uint4 gb1 = *reinterpret_cast<const uint4*>(b_src1);
    uint4 gb2 = (tid < 64) ? *reinterpret_cast<const uint4*>(b_src2) : (uint4){0,0,0,0};

    const int ntile = 5 - nh;             // nh=0: tiles 0-4, nh=1: tiles 5-8
    const int tbase = nh * 5;

    for (int kk = 0; kk < 512; kk += 32){
        uint4 pk;
        pk.x = f2bf(ga0.x) | ((unsigned)f2bf(ga0.y) << 16);
        pk.y = f2bf(ga0.z) | ((unsigned)f2bf(ga0.w) << 16);
        pk.z = f2bf(ga1.x) | ((unsigned)f2bf(ga1.y) << 16);
        pk.w = f2bf(ga1.z) | ((unsigned)f2bf(ga1.w) << 16);
        *reinterpret_cast<uint4*>(a_dst) = pk;
        *b_dst0 = gb0;
        *b_dst1 = gb1;
        if (tid < 64) *b_dst2 = gb2;
        __syncthreads();
        if (kk < 480){
            ga0 = *reinterpret_cast<const float4*>(a_src + kk + 32);
            ga1 = *reinterpret_cast<const float4*>(a_src + kk + 36);
            gb0 = *reinterpret_cast<const uint4*>(b_src0 + kk + 32);
            gb1 = *reinterpret_cast<const uint4*>(b_src1 + kk + 32);
            if (tid < 64) gb2 = *reinterpret_cast<const uint4*>(b_src2 + kk + 32);
        }
        bf16x8 a0 = ldfrag(&Af[(mh * 2    ) * 512 + lane * 8]);
        bf16x8 a1 = ldfrag(&Af[(mh * 2 + 1) * 512 + lane * 8]);
        #pragma unroll
        for (int t = 0; t < 5; t++){
            if (t < ntile){               // wave-uniform
                bf16x8 bfr = ldfrag(&Bf[(tbase + t) * 512 + lane * 8]);
                acc[t][0] = __builtin_amdgcn_mfma_f32_16x16x32_bf16(a0, bfr, acc[t][0], 0, 0, 0);
                acc[t][1] = __builtin_amdgcn_mfma_f32_16x16x32_bf16(a1, bfr, acc[t][1], 0, 0, 0);
            }
        }
        __syncthreads();
    }

    if (nh == 1){
        const float bs = bsum[m];         // m: 0=Σbq 1=Σbk 2=Σbv
        #pragma unroll
        for (int f = 0; f < 2; f++){
            #pragma unroll
            for (int i = 0; i < 4; i++){
                int rl = mh * 32 + f * 16 + q * 4 + i;
                float val = acc[3][f][i] + bs;
                float qsv = __shfl(val, (lane & 48));
                float ksv = __shfl(val, (lane & 48) | 1);
                float vsv = __shfl(val, (lane & 48) | 2);
                if (m == 0){
                    kzsh[rl] = (ksv == 0.f) ? 0.f : 1.f;
                    wvp[(size_t)r0 + rl] = (qsv == 0.f) ? 0.f : vsv;
                }
            }
        }
    }
    __syncthreads();

    if (nh == 0){
        float bqv[4];
        #pragma unroll
        for (int t = 0; t < 4; t++) bqv[t] = bq[t * 16 + m];
        const float bkv0 = bk[m];
        #pragma unroll
        for (int f = 0; f < 2; f++){
            #pragma unroll
            for (int i = 0; i < 4; i++){
                int rl = mh * 32 + f * 16 + q * 4 + i;
                size_t r = (size_t)r0 + rl;
                float kz = kzsh[rl];
                #pragma unroll
                for (int t = 0; t < 4; t++)
                    Qb[r * 64 + t * 16 + m] = f2bf((acc[t][f][i] + bqv[t]) * SCALE_LOG2E);
                Kb[r * 64 + m] = f2bf((acc[4][f][i] + bkv0) * kz);
            }
        }
    } else {
        float bkv[3];
        #pragma unroll
        for (int t = 0; t < 3; t++) bkv[t] = bk[16 + t * 16 + m];
        #pragma unroll
        for (int f = 0; f < 2; f++){
            #pragma unroll
            for (int i = 0; i < 4; i++){
                int rl = mh * 32 + f * 16 + q * 4 + i;
                size_t r = (size_t)r0 + rl;
                float kz = kzsh[rl];
                #pragma unroll
                for (int t = 0; t < 3; t++)
                    Kb[r * 64 + 16 + t * 16 + m] = f2bf((acc[t][f][i] + bkv[t]) * kz);
            }
        }
    }
}

// ---------------- attn_out: full-K per block -> c in LDS -> out contraction ----------
// Block: (b, 128 q-rows), 8 waves; wave w owns rows t0+w*16, loops ALL 2048 keys.
// K tiles double-buffered in frag order (1 barrier/tile). Then out phase in-block.
__global__ __launch_bounds__(512) void attn_out_kernel(
    const float* __restrict__ inp,
    const unsigned short* __restrict__ Qb, const unsigned short* __restrict__ Kb,
    const float* __restrict__ wvp, float* __restrict__ out)
{
    __shared__ __align__(16) unsigned short Kf[2][8 * 512]; // 2 bufs x 8 chunks x 1KB
    __shared__ float csh[128];
    const int tid = threadIdx.x;
    const int lane = tid & 63, wvid = tid >> 6;             // 8 waves
    const int m = lane & 15, q = lane >> 4;
    const int b  = blockIdx.y;
    const int t0 = blockIdx.x * 128;                        // block's 128 q-rows
    const size_t base = (size_t)b * T_;

    // wave's 16 q-rows
    const unsigned short* qp = &Qb[(base + t0 + wvid * 16 + m) * 64 + q * 8];
    bf16x8 a0 = ldfrag(qp), a1 = ldfrag(qp + 32);

    // wave wvid stages chunk wvid: key rows (wvid>>1)*16..+16, k-half (wvid&1)
    const unsigned short* ksrc = &Kb[(base + (wvid >> 1) * 16 + m) * 64 + (wvid & 1) * 32 + q * 8];
    const int k_off = wvid * 512 + lane * 8;
    uint4 stg = *reinterpret_cast<const uint4*>(ksrc);

    float num[4] = {0,0,0,0}, den[4] = {0,0,0,0};

    for (int it = 0; it < 32; it++){
        const int p = it & 1;
        *reinterpret_cast<uint4*>(&Kf[p][k_off]) = stg;
        __syncthreads();                  // dbuf: single barrier per tile
        if (it < 31) stg = *reinterpret_cast<const uint4*>(ksrc + (it + 1) * 4096);
        float w[4];
        #pragma unroll
        for (int st = 0; st < 4; st++) w[st] = wvp[base + it * 64 + st * 16 + m];
        #pragma unroll
        for (int st = 0; st < 4; st++){
            bf16x8 b0 = ldfrag(&Kf[p][(st * 2    ) * 512 + lane * 8]);
            bf16x8 b1 = ldfrag(&Kf[p][(st * 2 + 1) * 512 + lane * 8]);
            f32x4 z = (f32x4){0.f,0.f,0.f,0.f};
            z = __builtin_amdgcn_mfma_f32_16x16x32_bf16(a0, b0, z, 0, 0, 0);
            z = __builtin_amdgcn_mfma_f32_16x16x32_bf16(a1, b1, z, 0, 0, 0);
            float wst = w[st];
            #pragma unroll
            for (int i = 0; i < 4; i++){
                float e = exp2f(z[i]);                    // scale pre-folded into Qb
                den[i] += e;
                num[i] = fmaf(e, wst, num[i]);
            }
        }
    }
    #pragma unroll
    for (int s = 1; s < 16; s <<= 1){
        #pragma unroll
        for (int i = 0; i < 4; i++){
            num[i] += __shfl_xor(num[i], s);
            den[i] += __shfl_xor(den[i], s);
        }
    }
    __syncthreads();                      // Kf no longer needed; csh about to be written
    if (m == 0){
        #pragma unroll
        for (int i = 0; i < 4; i++)
            csh[wvid * 16 + q * 4 + i] = num[i] / den[i];
    }
    __syncthreads();

    // out phase: thread tid owns column tid; loop the block's 128 rows
    const float* ip = inp + (base + t0) * 512 + tid;
    float a = 0.f;
    #pragma unroll 8
    for (int t = 0; t < 128; t++)
        a = fmaf(ip[(size_t)t * 512], csh[t], a);
    atomicAdd(&out[b * 512 + tid], a);
}

extern "C" void kernel_launch(void* const* d_in, const int* in_sizes, int n_in,
                              void* d_out, int out_size, void* d_ws, size_t ws_size,
                              hipStream_t stream)
{
    const float* inp = (const float*)d_in[0];
    const float* Wq  = (const float*)d_in[1];
    const float* bq  = (const float*)d_in[2];
    const float* Wk  = (const float*)d_in[3];
    const float* bk  = (const float*)d_in[4];
    const float* Wv  = (const float*)d_in[5];
    const float* bv  = (const float*)d_in[6];
    float* out = (float*)d_out;

    char* ws = (char*)d_ws;
    unsigned short* WcT = (unsigned short*)(ws);
    float* bsum         = (float*)(ws + 147456);
    unsigned short* Qb  = (unsigned short*)(ws + 262144);
    unsigned short* Kb  = (unsigned short*)(ws + 4456448);
    float* wvp          = (float*)(ws + 8650752);

    setup_kernel<<<321, 256, 0, stream>>>(Wq, Wk, Wv, bq, bk, bv, WcT, bsum, out);
    proj_kernel<<<512, 256, 0, stream>>>(inp, WcT, bq, bk, bsum, Qb, Kb, wvp);
    attn_out_kernel<<<dim3(16, 16), 512, 0, stream>>>(inp, Qb, Kb, wvp, out);
}